// Round 2
// 1384.838 us; speedup vs baseline: 1.2105x; 1.2105x over previous
//
#include <hip/hip_runtime.h>
#include <hip/hip_fp16.h>
#include <math.h>

typedef unsigned short u16;
typedef __attribute__((ext_vector_type(8))) short bf16x8;   // 8 bf16 = 4 VGPR
typedef __attribute__((ext_vector_type(4))) float f32x4;

constexpr int B_ = 16;
constexpr int D_ = 512;
constexpr int N_ = 2048;
constexpr int S_ = 15;
constexpr int TOPK = 16;

// MFMA GEMM geometry: block = 64 rows x 256-col chunks (8 chunks).
// Virtual K' = 1536 = [A_hi*B_hi | A_lo*B_hi | A_hi*B_lo] over packed [hi|lo]
// operands of row length KP=1024 bf16. 4 waves, each owns a 64x64 tile
// (4x4 frags of 16x16x32 MFMA). lo*lo term omitted: rel err ~2^-18.
constexpr int BM = 64;
constexpr int BN = 256;
constexpr int BK = 32;
constexpr int NCH = N_ / BN;          // 8
constexpr int NKT = (3 * D_) / BK;    // 48
constexpr int KP  = 2 * D_;           // 1024 packed bf16 per row
constexpr int SCW = 132;              // sC row stride (128 + 4 pad)

// async global->LDS, 16 bytes per lane (dest = wave-uniform base + lane*16)
__device__ __forceinline__ void gl_lds16(const void* g, void* s) {
    __builtin_amdgcn_global_load_lds(
        (const __attribute__((address_space(1))) unsigned int*)g,
        (__attribute__((address_space(3))) unsigned int*)s, 16, 0, 0);
}

// ---------------------------------------------------------------------------
// Pack: fp32 [B][D][N] -> bf16 [B][N][1024] N-major, row = [hi(0..511)|lo].
// hi = bf16_rn(x), lo = bf16_rn(x - hi). 64k x 64n tiles through LDS.
// ---------------------------------------------------------------------------
__global__ __launch_bounds__(256) void packbf(
    const float* __restrict__ srcE, const float* __restrict__ tgtE,
    u16* __restrict__ srcP, u16* __restrict__ tgtP)
{
    const int t = threadIdx.x;
    const int b = blockIdx.z & 15, sel = blockIdx.z >> 4;
    const float* in = (sel ? tgtE : srcE) + (size_t)b * D_ * N_;
    u16* out = (sel ? tgtP : srcP) + (size_t)b * N_ * KP;
    const int n0 = blockIdx.x * 64, k0 = blockIdx.y * 64;

    __shared__ float T[64][69];   // [n][k], stride 69 breaks bank alignment

    #pragma unroll
    for (int it = 0; it < 4; it++) {
        int r = it * 16 + (t >> 4);           // k-row
        int c = (t & 15) * 4;                 // n-col
        float4 v = *(const float4*)&in[(size_t)(k0 + r) * N_ + n0 + c];
        T[c + 0][r] = v.x; T[c + 1][r] = v.y; T[c + 2][r] = v.z; T[c + 3][r] = v.w;
    }
    __syncthreads();

    const int nn = t >> 2, kc = (t & 3) * 16;
    __align__(16) u16 hi[16], lo[16];
    #pragma unroll
    for (int j = 0; j < 16; j++) {
        float x = T[nn][kc + j];
        unsigned u = __float_as_uint(x);
        unsigned hr = u + 0x7fff + ((u >> 16) & 1);     // rn-even to bf16
        u16 h = (u16)(hr >> 16);
        float hf = __uint_as_float((unsigned)h << 16);
        float xl = x - hf;
        unsigned ul = __float_as_uint(xl);
        unsigned lr = ul + 0x7fff + ((ul >> 16) & 1);
        hi[j] = h; lo[j] = (u16)(lr >> 16);
    }
    u16* op = out + (size_t)(n0 + nn) * KP + k0 + kc;
    *(int4*)op         = *(int4*)hi;  *(int4*)(op + 8)   = *(int4*)(hi + 8);
    *(int4*)(op + 512) = *(int4*)lo;  *(int4*)(op + 520) = *(int4*)(lo + 8);
}

// ---------------------------------------------------------------------------
// Pass 1: MFMA GEMM -> per-row 1/Z + sorted top-16 (adjusted by -log Z).
// Grid 512 blocks (XCD-swizzled), 256 threads. No E materialization.
//
// LDS tiles are [row][4 slots of 8 bf16] with phys slot = slot ^ ((row>>1)&3)
// (swizzle applied on the global SOURCE address at staging and on the LDS
// read offset). global_load_lds dest stays linear as required.
// ---------------------------------------------------------------------------
__global__ __launch_bounds__(256, 2) void gemm7(
    const u16* __restrict__ srcP, const u16* __restrict__ tgtP,
    float* __restrict__ rzbuf,            // [B][N] 1/Z
    float* __restrict__ topv,             // [B][N][16] sorted desc, l - logZ
    int*   __restrict__ topc)             // [B][N][16]
{
    __shared__ __align__(16) float sC[BM * SCW];     // 33.8 KB epilogue half
    __shared__ __align__(16) u16 sA[2 * BM * BK];    // 8 KB  (2 bufs)
    __shared__ __align__(16) u16 sB[2 * BN * BK];    // 32 KB (2 bufs)

    const int tid = threadIdx.x;
    const int w = tid >> 6, lane = tid & 63;
    const int sr = lane >> 2, q = lane & 3;
    // XCD-chunked bijective swizzle (512 = 8 XCD * 64): each XCD ~2 batches
    const int bid = blockIdx.x;
    const int swz = (bid & 7) * 64 + (bid >> 3);
    const int b  = swz >> 5;
    const int s0 = (swz & 31) * BM;
    const float scale = 0.044194173824159216f;       // 1/sqrt(512)

    const u16* srcPb = srcP + (size_t)b * N_ * KP;
    const u16* tgtPb = tgtP + (size_t)b * N_ * KP;

    // staging: phys 16B-slot (lane&3) at row base+(lane>>2) holds logical
    // k-slot (lane&3)^((lane>>3)&3) == (lane&3)^((row>>1)&3)
    const int sls = ((lane & 3) ^ ((lane >> 3) & 3)) * 8;
    const u16* pA = srcPb + (size_t)(s0 + w * 16 + (lane >> 2)) * KP + sls;
    const u16* pB = tgtPb + (size_t)(w * 64 + (lane >> 2)) * KP + sls;
    // fragment read: row = 16i + (l&15), phys slot = (l>>4) ^ ((row>>1)&3)
    const int aro = (lane & 15) * BK + (((lane >> 4) ^ ((lane >> 1) & 3)) * 8);

    // virtual k-tile kt -> packed offsets: sections [hi*hi | lo*hi | hi*lo]
    auto stage = [&](int bi, int kt, int c0) {
        const int akb = (kt < 32 ? kt : kt - 32) * BK;   // A: hi,lo,hi
        const int bkb = (kt < 16 ? kt : kt - 16) * BK;   // B: hi,hi,lo
        gl_lds16(pA + akb, &sA[bi * (BM * BK) + w * 512]);
        #pragma unroll
        for (int ii = 0; ii < 4; ii++)
            gl_lds16(pB + (size_t)(c0 + ii * 16) * KP + bkb,
                     &sB[bi * (BN * BK) + (w * 4 + ii) * 512]);
    };

    float z_loc = 0.f;
    float tv[TOPK]; int tc16[TOPK];
    float tmin = -1e30f; int tminslot = 0, tmincol = 0x7fffffff;
    #pragma unroll
    for (int k = 0; k < TOPK; k++) { tv[k] = -1e30f; tc16[k] = 0x7fffffff; }

    stage(0, 0, 0);

    for (int ch = 0; ch < NCH; ch++) {
        const int c0 = ch * BN;
        f32x4 acc[4][4];
        #pragma unroll
        for (int i = 0; i < 4; i++)
            #pragma unroll
            for (int j = 0; j < 4; j++) acc[i][j] = (f32x4){0.f, 0.f, 0.f, 0.f};

        for (int kt = 0; kt < NKT; kt++) {
            __syncthreads();   // buffer (kt&1) staged (vmcnt drained) & prev reads done
            if (kt < NKT - 1)      stage((kt + 1) & 1, kt + 1, c0);
            else if (ch < NCH - 1) stage(0, 0, c0 + BN);
            const u16* Ab = &sA[(kt & 1) * (BM * BK)];
            const u16* Bb = &sB[(kt & 1) * (BN * BK)];
            bf16x8 af[4], bf[4];
            #pragma unroll
            for (int i = 0; i < 4; i++)
                af[i] = *(const bf16x8*)&Ab[i * 512 + aro];
            #pragma unroll
            for (int j = 0; j < 4; j++)
                bf[j] = *(const bf16x8*)&Bb[w * 2048 + j * 512 + aro];
            #pragma unroll
            for (int i = 0; i < 4; i++)
                #pragma unroll
                for (int j = 0; j < 4; j++)
                    acc[i][j] = __builtin_amdgcn_mfma_f32_16x16x32_bf16(
                        af[i], bf[j], acc[i][j], 0, 0, 0);
        }

        // ---- epilogue: two 128-col halves through shared sC; wave w owns
        // stats rows [w*16, w*16+16) across ALL cols (persistent registers) ----
        #pragma unroll 1
        for (int h = 0; h < 2; h++) {
            __syncthreads();                       // sC free
            if ((w >> 1) == h) {                   // waves 2h,2h+1 own these cols
                const int cb = (w & 1) * 64;
                #pragma unroll
                for (int i = 0; i < 4; i++)
                    #pragma unroll
                    for (int j = 0; j < 4; j++)
                        #pragma unroll
                        for (int r = 0; r < 4; r++)
                            sC[(i * 16 + (lane >> 4) * 4 + r) * SCW + cb + j * 16 + (lane & 15)]
                                = acc[i][j][r] * scale;
            }
            __syncthreads();                       // sC filled
            // stats: 4 lanes/row (q strips), cols q*4 + m*16 (+e)
            const float* rowp = &sC[(w * 16 + sr) * SCW];
            #pragma unroll 1
            for (int m = 0; m < 8; m++) {
                float4 v4 = *(const float4*)&rowp[q * 4 + m * 16];
                const float vv[4] = {v4.x, v4.y, v4.z, v4.w};
                #pragma unroll
                for (int e = 0; e < 4; e++) {
                    float v = vv[e];
                    int c = c0 + h * 128 + q * 4 + m * 16 + e;
                    z_loc += expf(v);
                    bool ins = (v > tmin) || (v == tmin && c < tmincol);
                    if (ins) {
                        #pragma unroll
                        for (int k = 0; k < TOPK; k++)
                            if (k == tminslot) { tv[k] = v; tc16[k] = c; }
                        tmin = tv[0]; tmincol = tc16[0]; tminslot = 0;
                        #pragma unroll
                        for (int k = 1; k < TOPK; k++) {
                            bool worse = (tv[k] < tmin) || (tv[k] == tmin && tc16[k] > tmincol);
                            if (worse) { tmin = tv[k]; tmincol = tc16[k]; tminslot = k; }
                        }
                    }
                }
            }
        }
    }

    // ---- final merge: wave-private inside own 16-row sC region (2112 f):
    //   cbw ints [0,1024) | vbw floats [1024,2048) | zqw floats [2048,2112)
    // After the last "sC filled" barrier only wave w touches its own rows.
    float* sCw = &sC[w * 16 * SCW];
    int*   cbw = (int*)sCw;
    float* vbw = sCw + 1024;
    float* zqw = sCw + 2048;
    zqw[lane] = z_loc;
    #pragma unroll
    for (int k = 0; k < TOPK; k++) {
        vbw[lane * 16 + k] = tv[k];
        cbw[lane * 16 + k] = tc16[k];
    }
    if (q == 0) {
        float Z = zqw[lane] + zqw[lane + 1] + zqw[lane + 2] + zqw[lane + 3];
        float lz = logf(Z);
        const int grow = s0 + w * 16 + sr;
        rzbuf[b * N_ + grow] = 1.0f / Z;
        tmin = -1e30f; tminslot = 0; tmincol = 0x7fffffff;
        #pragma unroll
        for (int k = 0; k < TOPK; k++) { tv[k] = -1e30f; tc16[k] = 0x7fffffff; }
        for (int qq = 0; qq < 4; qq++) {
            #pragma unroll 1
            for (int k = 0; k < TOPK; k++) {
                float v = vbw[(lane + qq) * 16 + k];
                int c = cbw[(lane + qq) * 16 + k];
                bool ins = (v > tmin) || (v == tmin && c < tmincol);
                if (ins) {
                    #pragma unroll
                    for (int k2 = 0; k2 < TOPK; k2++)
                        if (k2 == tminslot) { tv[k2] = v; tc16[k2] = c; }
                    tmin = tv[0]; tmincol = tc16[0]; tminslot = 0;
                    #pragma unroll
                    for (int k2 = 1; k2 < TOPK; k2++) {
                        bool worse = (tv[k2] < tmin) || (tv[k2] == tmin && tc16[k2] > tmincol);
                        if (worse) { tmin = tv[k2]; tmincol = tc16[k2]; tminslot = k2; }
                    }
                }
            }
        }
        unsigned used = 0;
        size_t rowbase = ((size_t)b * N_ + grow) * TOPK;
        for (int o = 0; o < TOPK; o++) {
            float bvv = -1e31f; int bcc = 0x7fffffff; int bk = 0;
            #pragma unroll
            for (int k = 0; k < TOPK; k++) {
                bool u = (used >> k) & 1u;
                bool better = !u && ((tv[k] > bvv) || (tv[k] == bvv && tc16[k] < bcc));
                if (better) { bvv = tv[k]; bcc = tc16[k]; bk = k; }
            }
            used |= 1u << bk;
            topv[rowbase + o] = bvv - lz;
            topc[rowbase + o] = bcc;
        }
    }
}

// ---------------------------------------------------------------------------
// Pass 2: recompute the same GEMM; colsum[b][t] += sum_s exp(l[s][t])*rz[s].
// Per-wave: exp+weight from acc regs, reduce rows via shfl, 1 atomic/col.
// ---------------------------------------------------------------------------
__global__ __launch_bounds__(256, 2) void gemm8(
    const u16* __restrict__ srcP, const u16* __restrict__ tgtP,
    const float* __restrict__ rzbuf, float* __restrict__ colsum)
{
    __shared__ __align__(16) u16 sA[2 * BM * BK];    // 8 KB
    __shared__ __align__(16) u16 sB[2 * BN * BK];    // 32 KB
    __shared__ float sRZ[BM];

    const int tid = threadIdx.x;
    const int w = tid >> 6, lane = tid & 63;
    const int bid = blockIdx.x;
    const int swz = (bid & 7) * 64 + (bid >> 3);
    const int b  = swz >> 5;
    const int s0 = (swz & 31) * BM;
    const float scale = 0.044194173824159216f;

    const u16* srcPb = srcP + (size_t)b * N_ * KP;
    const u16* tgtPb = tgtP + (size_t)b * N_ * KP;

    if (tid < BM) sRZ[tid] = rzbuf[b * N_ + s0 + tid];  // first k-loop barrier orders this

    const int sls = ((lane & 3) ^ ((lane >> 3) & 3)) * 8;
    const u16* pA = srcPb + (size_t)(s0 + w * 16 + (lane >> 2)) * KP + sls;
    const u16* pB = tgtPb + (size_t)(w * 64 + (lane >> 2)) * KP + sls;
    const int aro = (lane & 15) * BK + (((lane >> 4) ^ ((lane >> 1) & 3)) * 8);

    auto stage = [&](int bi, int kt, int c0) {
        const int akb = (kt < 32 ? kt : kt - 32) * BK;
        const int bkb = (kt < 16 ? kt : kt - 16) * BK;
        gl_lds16(pA + akb, &sA[bi * (BM * BK) + w * 512]);
        #pragma unroll
        for (int ii = 0; ii < 4; ii++)
            gl_lds16(pB + (size_t)(c0 + ii * 16) * KP + bkb,
                     &sB[bi * (BN * BK) + (w * 4 + ii) * 512]);
    };

    stage(0, 0, 0);

    for (int ch = 0; ch < NCH; ch++) {
        const int c0 = ch * BN;
        f32x4 acc[4][4];
        #pragma unroll
        for (int i = 0; i < 4; i++)
            #pragma unroll
            for (int j = 0; j < 4; j++) acc[i][j] = (f32x4){0.f, 0.f, 0.f, 0.f};

        for (int kt = 0; kt < NKT; kt++) {
            __syncthreads();
            if (kt < NKT - 1)      stage((kt + 1) & 1, kt + 1, c0);
            else if (ch < NCH - 1) stage(0, 0, c0 + BN);
            const u16* Ab = &sA[(kt & 1) * (BM * BK)];
            const u16* Bb = &sB[(kt & 1) * (BN * BK)];
            bf16x8 af[4], bf[4];
            #pragma unroll
            for (int i = 0; i < 4; i++)
                af[i] = *(const bf16x8*)&Ab[i * 512 + aro];
            #pragma unroll
            for (int j = 0; j < 4; j++)
                bf[j] = *(const bf16x8*)&Bb[w * 2048 + j * 512 + aro];
            #pragma unroll
            for (int i = 0; i < 4; i++)
                #pragma unroll
                for (int j = 0; j < 4; j++)
                    acc[i][j] = __builtin_amdgcn_mfma_f32_16x16x32_bf16(
                        af[i], bf[j], acc[i][j], 0, 0, 0);
        }

        // epilogue: lane covers col j*16+(lane&15), rows i*16+(lane>>4)*4+r
        #pragma unroll
        for (int j = 0; j < 4; j++) {
            float s = 0.f;
            #pragma unroll
            for (int i = 0; i < 4; i++)
                #pragma unroll
                for (int r = 0; r < 4; r++)
                    s += expf(acc[i][j][r] * scale) * sRZ[i * 16 + (lane >> 4) * 4 + r];
            s += __shfl_xor(s, 16);
            s += __shfl_xor(s, 32);
            if (lane < 16)
                atomicAdd(&colsum[b * N_ + c0 + w * 64 + j * 16 + lane], s);
        }
    }
}

// ---------------------------------------------------------------------------
// Greedy match: per-row current-best + rescan on collision. 1 block/batch.
// ---------------------------------------------------------------------------
__global__ __launch_bounds__(256) void match2(
    const float* __restrict__ topv, const int* __restrict__ topc,
    int* __restrict__ mrow, int* __restrict__ mcol)
{
    const int b = blockIdx.x, tid = threadIdx.x;
    __shared__ float bv[N_];
    __shared__ int bc[N_];
    __shared__ int sup[16];
    __shared__ float rv[256];
    __shared__ int rr[256];

    for (int r = tid; r < N_; r += 256) {
        bv[r] = topv[((size_t)b * N_ + r) * TOPK];
        bc[r] = topc[((size_t)b * N_ + r) * TOPK];
    }
    __syncthreads();

    for (int it = 0; it < S_; it++) {
        float mv = -1e30f; int mr = 0x7fffffff;
        #pragma unroll
        for (int j = 0; j < 8; j++) {
            int r = tid + j * 256;
            float v = bv[r];
            if (v > mv) { mv = v; mr = r; }
        }
        rv[tid] = mv; rr[tid] = mr;
        __syncthreads();
        for (int off = 128; off; off >>= 1) {
            if (tid < off) {
                float v2 = rv[tid + off];
                if (v2 > rv[tid] || (v2 == rv[tid] && rr[tid + off] < rr[tid])) {
                    rv[tid] = v2; rr[tid] = rr[tid + off];
                }
            }
            __syncthreads();
        }
        if (tid == 0) {
            int R = rr[0]; int C = bc[R];
            mrow[b * S_ + it] = R; mcol[b * S_ + it] = C;
            sup[it] = C;
            bv[R] = -1e30f;
        }
        __syncthreads();
        const int C = sup[it];
        for (int r = tid; r < N_; r += 256) {
            if (bc[r] == C && bv[r] > -1e29f) {
                float nv = -1e30f; int nc = 0x7fffffff;
                const float* tvp = &topv[((size_t)b * N_ + r) * TOPK];
                const int* tcp = &topc[((size_t)b * N_ + r) * TOPK];
                for (int k = 0; k < TOPK; k++) {
                    int c2 = tcp[k];
                    bool bad = false;
                    for (int qq = 0; qq <= it; qq++) bad = bad || (sup[qq] == c2);
                    if (!bad) { nv = tvp[k]; nc = c2; break; }
                }
                bv[r] = nv; bc[r] = nc;
            }
        }
        __syncthreads();
    }
}

// ---------------------------------------------------------------------------
// Final: means, Kabsch (3x3 Jacobi SVD in fp64), R and t. One block per batch.
// ---------------------------------------------------------------------------
__global__ void finish_kernel(const float* __restrict__ src,
                              const float* __restrict__ tgt,
                              const float* __restrict__ colsum,
                              const int* __restrict__ mrow,
                              const int* __restrict__ mcol,
                              float* __restrict__ out)
{
    const int b = blockIdx.x;
    const int tid = threadIdx.x;
    __shared__ float red[256];
    __shared__ float res[6];

    float ls[3] = {0, 0, 0}, lc[3] = {0, 0, 0};
    for (int n = tid; n < N_; n += 256) {
        float cs = colsum[b * N_ + n];
        #pragma unroll
        for (int j = 0; j < 3; j++) {
            ls[j] += src[(size_t)(b * N_ + n) * 3 + j];
            lc[j] += tgt[(size_t)(b * N_ + n) * 3 + j] * cs;
        }
    }
    for (int j = 0; j < 6; j++) {
        red[tid] = (j < 3) ? ls[j] : lc[j - 3];
        __syncthreads();
        for (int off = 128; off; off >>= 1) {
            if (tid < off) red[tid] += red[tid + off];
            __syncthreads();
        }
        if (tid == 0) res[j] = red[0] / (float)N_;
        __syncthreads();
    }

    if (tid == 0) {
        double ps[S_][3], pt[S_][3];
        double ms[3] = {0, 0, 0}, mt[3] = {0, 0, 0};
        for (int s = 0; s < S_; s++) {
            int r = mrow[b * S_ + s], c = mcol[b * S_ + s];
            for (int j = 0; j < 3; j++) {
                ps[s][j] = (double)src[(size_t)(b * N_ + r) * 3 + j];
                pt[s][j] = (double)tgt[(size_t)(b * N_ + c) * 3 + j];
                ms[j] += ps[s][j]; mt[j] += pt[s][j];
            }
        }
        for (int j = 0; j < 3; j++) { ms[j] /= S_; mt[j] /= S_; }
        double H[3][3] = {{0,0,0},{0,0,0},{0,0,0}};
        for (int s = 0; s < S_; s++)
            for (int i = 0; i < 3; i++)
                for (int j = 0; j < 3; j++)
                    H[i][j] += (ps[s][i] - ms[i]) * (pt[s][j] - mt[j]);

        double A[3][3], Vv[3][3] = {{1,0,0},{0,1,0},{0,0,1}};
        for (int i = 0; i < 3; i++)
            for (int j = 0; j < 3; j++) {
                double acc = 0;
                for (int k = 0; k < 3; k++) acc += H[k][i] * H[k][j];
                A[i][j] = acc;
            }
        for (int sweep = 0; sweep < 30; sweep++) {
            double off = fabs(A[0][1]) + fabs(A[0][2]) + fabs(A[1][2]);
            if (off < 1e-30) break;
            for (int pair = 0; pair < 3; pair++) {
                int p = (pair == 2) ? 1 : 0;
                int q = (pair == 0) ? 1 : 2;
                double apq = A[p][q];
                if (fabs(apq) < 1e-300) continue;
                double theta = (A[q][q] - A[p][p]) / (2.0 * apq);
                double tt = ((theta >= 0) ? 1.0 : -1.0) / (fabs(theta) + sqrt(theta * theta + 1.0));
                double cc = 1.0 / sqrt(tt * tt + 1.0);
                double ssn = tt * cc;
                for (int k = 0; k < 3; k++) {
                    double akp = A[k][p], akq = A[k][q];
                    A[k][p] = cc * akp - ssn * akq;
                    A[k][q] = ssn * akp + cc * akq;
                }
                for (int k = 0; k < 3; k++) {
                    double apk = A[p][k], aqk = A[q][k];
                    A[p][k] = cc * apk - ssn * aqk;
                    A[q][k] = ssn * apk + cc * aqk;
                }
                for (int k = 0; k < 3; k++) {
                    double vkp = Vv[k][p], vkq = Vv[k][q];
                    Vv[k][p] = cc * vkp - ssn * vkq;
                    Vv[k][q] = ssn * vkp + cc * vkq;
                }
            }
        }
        double wv[3] = {A[0][0], A[1][1], A[2][2]};
        for (int a = 0; a < 2; a++)
            for (int b2 = a + 1; b2 < 3; b2++)
                if (wv[b2] > wv[a]) {
                    double tw = wv[a]; wv[a] = wv[b2]; wv[b2] = tw;
                    for (int k = 0; k < 3; k++) {
                        double tv_ = Vv[k][a]; Vv[k][a] = Vv[k][b2]; Vv[k][b2] = tv_;
                    }
                }
        double U[3][3];
        for (int k = 0; k < 3; k++) {
            double u[3], nrm = 0;
            for (int i = 0; i < 3; i++) {
                double acc = 0;
                for (int j = 0; j < 3; j++) acc += H[i][j] * Vv[j][k];
                u[i] = acc; nrm += acc * acc;
            }
            nrm = sqrt(nrm);
            if (nrm < 1e-300) nrm = 1e-300;
            for (int i = 0; i < 3; i++) U[i][k] = u[i] / nrm;
        }
        double r[3][3];
        for (int i = 0; i < 3; i++)
            for (int j = 0; j < 3; j++) {
                double acc = 0;
                for (int k = 0; k < 3; k++) acc += Vv[i][k] * U[j][k];
                r[i][j] = acc;
            }
        double det = r[0][0] * (r[1][1] * r[2][2] - r[1][2] * r[2][1])
                   - r[0][1] * (r[1][0] * r[2][2] - r[1][2] * r[2][0])
                   + r[0][2] * (r[1][0] * r[2][1] - r[1][1] * r[2][0]);
        if (det < 0.0) {
            for (int i = 0; i < 3; i++)
                for (int j = 0; j < 3; j++)
                    r[i][j] -= 2.0 * Vv[i][2] * U[j][2];
        }
        double smean[3] = {(double)res[0], (double)res[1], (double)res[2]};
        double cmean[3] = {(double)res[3], (double)res[4], (double)res[5]};
        for (int i = 0; i < 3; i++)
            for (int j = 0; j < 3; j++)
                out[b * 9 + i * 3 + j] = (float)r[i][j];
        for (int i = 0; i < 3; i++) {
            double acc = cmean[i];
            for (int j = 0; j < 3; j++) acc -= r[i][j] * smean[j];
            out[B_ * 9 + b * 3 + i] = (float)acc;
        }
    }
}

// ---------------------------------------------------------------------------
extern "C" void kernel_launch(void* const* d_in, const int* in_sizes, int n_in,
                              void* d_out, int out_size, void* d_ws, size_t ws_size,
                              hipStream_t stream)
{
    const float* srcE = (const float*)d_in[0];
    const float* tgtE = (const float*)d_in[1];
    const float* src  = (const float*)d_in[2];
    const float* tgt  = (const float*)d_in[3];
    float* out = (float*)d_out;
    char* ws = (char*)d_ws;

    // workspace: 128 MiB packed + 4.25 MiB stats = 132.25 MiB total
    // (same footprint as the previously-passing version; no lhalf)
    const size_t szP = (size_t)B_ * N_ * KP * sizeof(u16);      // 64 MiB each
    u16* srcP = (u16*)ws;
    u16* tgtP = (u16*)(ws + szP);
    size_t off = 2 * szP;
    float* rzbuf  = (float*)(ws + off); off += (size_t)B_ * N_ * sizeof(float);
    float* topv   = (float*)(ws + off); off += (size_t)B_ * N_ * TOPK * sizeof(float);
    int*   topc   = (int*)(ws + off);   off += (size_t)B_ * N_ * TOPK * sizeof(int);
    float* colsum = (float*)(ws + off); off += (size_t)B_ * N_ * sizeof(float);
    int*   mrow   = (int*)(ws + off);   off += 1024;
    int*   mcol   = (int*)(ws + off);

    hipMemsetAsync(colsum, 0, (size_t)B_ * N_ * sizeof(float), stream);

    packbf<<<dim3(N_ / 64, D_ / 64, 2 * B_), 256, 0, stream>>>(srcE, tgtE, srcP, tgtP);
    gemm7<<<dim3((N_ / BM) * B_), 256, 0, stream>>>(srcP, tgtP, rzbuf, topv, topc);
    gemm8<<<dim3((N_ / BM) * B_), 256, 0, stream>>>(srcP, tgtP, rzbuf, colsum);
    match2<<<B_, 256, 0, stream>>>(topv, topc, mrow, mcol);
    finish_kernel<<<B_, 256, 0, stream>>>(src, tgt, colsum, mrow, mcol, out);
}

// Round 3
// 1217.746 us; speedup vs baseline: 1.3766x; 1.1372x over previous
//
#include <hip/hip_runtime.h>
#include <hip/hip_fp16.h>
#include <math.h>

typedef unsigned short u16;
typedef __attribute__((ext_vector_type(8))) short bf16x8;   // 8 bf16 = 4 VGPR
typedef __attribute__((ext_vector_type(4))) float f32x4;

constexpr int B_ = 16;
constexpr int D_ = 512;
constexpr int N_ = 2048;
constexpr int S_ = 15;
constexpr int TOPK = 16;

// Packed bf16 hi/lo operands: row length KP = 1024 (hi 0..511 | lo 512..1023).
// GEMM: BM=128 rows/block, 256-col chunks, BK=32, 512 thr (8 waves of 64x64).
// Virtual K per chunk = 16 P-steps {Ah,Al,Bh staged; Ah*Bh + Al*Bh} +
//                       16 Q-steps {Ah,Bl staged; Ah*Bl}.
// Bh staged once (shared by both P sections) -> staging traffic 1.84 GB
// vs 3.9 GB for the round-2 geometry.
constexpr int BK  = 32;
constexpr int KP  = 2 * D_;           // 1024
constexpr int SCW = 132;              // sC row stride (128 + 4 pad)
constexpr int BN7 = 256;              // chunk width
constexpr int NCH7 = N_ / BN7;        // 8

// async global->LDS, 16 bytes per lane (dest = wave-uniform base + lane*16)
__device__ __forceinline__ void gl_lds16(const void* g, void* s) {
    __builtin_amdgcn_global_load_lds(
        (const __attribute__((address_space(1))) unsigned int*)g,
        (__attribute__((address_space(3))) unsigned int*)s, 16, 0, 0);
}

// ---------------------------------------------------------------------------
// Pack: fp32 [B][D][N] -> bf16 [B][N][1024] N-major, row = [hi(0..511)|lo].
// hi = bf16_rn(x), lo = bf16_rn(x - hi). 64k x 64n tiles through LDS.
// ---------------------------------------------------------------------------
__global__ __launch_bounds__(256) void packbf(
    const float* __restrict__ srcE, const float* __restrict__ tgtE,
    u16* __restrict__ srcP, u16* __restrict__ tgtP)
{
    const int t = threadIdx.x;
    const int b = blockIdx.z & 15, sel = blockIdx.z >> 4;
    const float* in = (sel ? tgtE : srcE) + (size_t)b * D_ * N_;
    u16* out = (sel ? tgtP : srcP) + (size_t)b * N_ * KP;
    const int n0 = blockIdx.x * 64, k0 = blockIdx.y * 64;

    __shared__ float T[64][69];   // [n][k], stride 69 breaks bank alignment

    #pragma unroll
    for (int it = 0; it < 4; it++) {
        int r = it * 16 + (t >> 4);           // k-row
        int c = (t & 15) * 4;                 // n-col
        float4 v = *(const float4*)&in[(size_t)(k0 + r) * N_ + n0 + c];
        T[c + 0][r] = v.x; T[c + 1][r] = v.y; T[c + 2][r] = v.z; T[c + 3][r] = v.w;
    }
    __syncthreads();

    const int nn = t >> 2, kc = (t & 3) * 16;
    __align__(16) u16 hi[16], lo[16];
    #pragma unroll
    for (int j = 0; j < 16; j++) {
        float x = T[nn][kc + j];
        unsigned u = __float_as_uint(x);
        unsigned hr = u + 0x7fff + ((u >> 16) & 1);     // rn-even to bf16
        u16 h = (u16)(hr >> 16);
        float hf = __uint_as_float((unsigned)h << 16);
        float xl = x - hf;
        unsigned ul = __float_as_uint(xl);
        unsigned lr = ul + 0x7fff + ((ul >> 16) & 1);
        hi[j] = h; lo[j] = (u16)(lr >> 16);
    }
    u16* op = out + (size_t)(n0 + nn) * KP + k0 + kc;
    *(int4*)op         = *(int4*)hi;  *(int4*)(op + 8)   = *(int4*)(hi + 8);
    *(int4*)(op + 512) = *(int4*)lo;  *(int4*)(op + 520) = *(int4*)(lo + 8);
}

// ---------------------------------------------------------------------------
// Pass 1: MFMA GEMM -> per-row 1/Z + sorted top-16 (adjusted by -log Z).
// Grid 256 (16 rowblocks x 16 batches, XCD-chunked), 512 threads.
// LDS: 64 KB staging (2 bufs of {Ah 8K | Al 8K | B 16K}) + 67.6 KB sC.
// Tile rows hold 4 swizzled 16B slots: phys slot p = logical ^ ((row>>1)&3),
// applied on the global source at staging and on the LDS read offset.
// ---------------------------------------------------------------------------
__global__ __launch_bounds__(512, 2) void gemm7(
    const u16* __restrict__ srcP, const u16* __restrict__ tgtP,
    float* __restrict__ rzbuf,            // [B][N] 1/Z
    float* __restrict__ topv,             // [B][N][16] sorted desc, l - logZ
    int*   __restrict__ topc)             // [B][N][16]
{
    __shared__ __align__(16) u16 sS[2 * 16384];      // 64 KB staging
    __shared__ __align__(16) float sC[128 * SCW];    // 67.6 KB epilogue

    const int tid = threadIdx.x;
    const int w = tid >> 6, lane = tid & 63;
    const int wr = w >> 2, wc = w & 3;               // wave tile: rows wr*64, cols wc*64
    const int sr = lane >> 2, q = lane & 3;
    // XCD-chunked swizzle: 256 blocks = 8 XCD * 32; each XCD owns 2 batches
    const int bid = blockIdx.x;
    const int swz = (bid & 7) * 32 + (bid >> 3);
    const int b  = swz >> 4;
    const int s0 = (swz & 15) * 128;
    const float scale = 0.044194173824159216f;       // 1/sqrt(512)

    const u16* srcPb = srcP + (size_t)b * N_ * KP;
    const u16* tgtPb = tgtP + (size_t)b * N_ * KP;

    // staging: lane -> row base+(lane>>2), phys slot lane&3 holds logical
    // slot (lane&3)^((lane>>3)&3); dest = wave base + lane*16B (linear)
    const int sls = ((lane & 3) ^ ((lane >> 3) & 3)) * 8;
    const u16* pAh = srcPb + (size_t)(s0 + w * 16 + (lane >> 2)) * KP + sls;
    const u16* pB  = tgtPb + (size_t)(w * 16 + (lane >> 2)) * KP + sls;
    // fragment read: row = 16i + (l&15), phys slot = (l>>4) ^ ((row>>1)&3)
    const int aro = (lane & 15) * BK + (((lane >> 4) ^ ((lane >> 1) & 3)) * 8);

    // step s in [0,32): s<16 -> P(t=s): Ah,Al,Bh ; s>=16 -> Q(t=s-16): Ah,Bl
    auto stage = [&](int bi, int s, int c0) {
        u16* base = &sS[bi * 16384];
        const int t32 = (s & 15) * BK;
        gl_lds16(pAh + t32, base + w * 512);                          // Ah
        if (s < 16) {
            gl_lds16(pAh + 512 + t32, base + 4096 + w * 512);         // Al
            gl_lds16(pB + (size_t)c0 * KP + t32,         base + 8192 + w * 512);
            gl_lds16(pB + (size_t)(c0 + 128) * KP + t32, base + 12288 + w * 512);
        } else {
            gl_lds16(pB + (size_t)c0 * KP + 512 + t32,         base + 8192 + w * 512);
            gl_lds16(pB + (size_t)(c0 + 128) * KP + 512 + t32, base + 12288 + w * 512);
        }
    };

    float z_loc = 0.f;
    float tv[TOPK]; int tc16[TOPK];
    float tmin = -1e30f; int tminslot = 0, tmincol = 0x7fffffff;
    #pragma unroll
    for (int k = 0; k < TOPK; k++) { tv[k] = -1e30f; tc16[k] = 0x7fffffff; }

    stage(0, 0, 0);

    for (int ch = 0; ch < NCH7; ch++) {
        const int c0 = ch * BN7;
        f32x4 acc[4][4];
        #pragma unroll
        for (int i = 0; i < 4; i++)
            #pragma unroll
            for (int j = 0; j < 4; j++) acc[i][j] = (f32x4){0.f, 0.f, 0.f, 0.f};

        for (int s = 0; s < 32; s++) {
            __syncthreads();   // buf (s&1) staged (vmcnt drained) & prev reads done
            if (s < 31)              stage((s + 1) & 1, s + 1, c0);
            else if (ch < NCH7 - 1)  stage(0, 0, c0 + BN7);
            const u16* base = &sS[(s & 1) * 16384];
            bf16x8 afr[4], bfr[4];
            #pragma unroll
            for (int j = 0; j < 4; j++)
                bfr[j] = *(const bf16x8*)&base[8192 + wc * 2048 + j * 512 + aro];
            #pragma unroll
            for (int i = 0; i < 4; i++)
                afr[i] = *(const bf16x8*)&base[wr * 2048 + i * 512 + aro];
            #pragma unroll
            for (int i = 0; i < 4; i++)
                #pragma unroll
                for (int j = 0; j < 4; j++)
                    acc[i][j] = __builtin_amdgcn_mfma_f32_16x16x32_bf16(
                        afr[i], bfr[j], acc[i][j], 0, 0, 0);
            if (s < 16) {   // P-step: second A section (lo) vs same Bh
                #pragma unroll
                for (int i = 0; i < 4; i++)
                    afr[i] = *(const bf16x8*)&base[4096 + wr * 2048 + i * 512 + aro];
                #pragma unroll
                for (int i = 0; i < 4; i++)
                    #pragma unroll
                    for (int j = 0; j < 4; j++)
                        acc[i][j] = __builtin_amdgcn_mfma_f32_16x16x32_bf16(
                            afr[i], bfr[j], acc[i][j], 0, 0, 0);
            }
        }

        // ---- epilogue: two 128-col halves through sC; wave w owns stats
        // rows [w*16, w*16+16) across all cols (persistent registers) ----
        #pragma unroll 1
        for (int h = 0; h < 2; h++) {
            __syncthreads();                       // prev half's reads done
            if ((wc >> 1) == h) {                  // 4 waves own these 128 cols
                const int cb = (wc & 1) * 64;
                #pragma unroll
                for (int i = 0; i < 4; i++)
                    #pragma unroll
                    for (int j = 0; j < 4; j++)
                        #pragma unroll
                        for (int r = 0; r < 4; r++)
                            sC[(wr * 64 + i * 16 + (lane >> 4) * 4 + r) * SCW
                               + cb + j * 16 + (lane & 15)] = acc[i][j][r] * scale;
            }
            __syncthreads();                       // sC filled
            const float* rowp = &sC[(w * 16 + sr) * SCW];
            #pragma unroll 1
            for (int m = 0; m < 8; m++) {
                float4 v4 = *(const float4*)&rowp[q * 4 + m * 16];
                const float vv[4] = {v4.x, v4.y, v4.z, v4.w};
                #pragma unroll
                for (int e = 0; e < 4; e++) {
                    float v = vv[e];
                    int c = c0 + h * 128 + q * 4 + m * 16 + e;
                    z_loc += expf(v);
                    bool ins = (v > tmin) || (v == tmin && c < tmincol);
                    if (ins) {
                        #pragma unroll
                        for (int k = 0; k < TOPK; k++)
                            if (k == tminslot) { tv[k] = v; tc16[k] = c; }
                        tmin = tv[0]; tmincol = tc16[0]; tminslot = 0;
                        #pragma unroll
                        for (int k = 1; k < TOPK; k++) {
                            bool worse = (tv[k] < tmin) || (tv[k] == tmin && tc16[k] > tmincol);
                            if (worse) { tmin = tv[k]; tmincol = tc16[k]; tminslot = k; }
                        }
                    }
                }
            }
        }
    }

    // ---- final merge: wave-private inside own 16-row sC slice (2112 f):
    //   cbw ints [0,1024) | vbw floats [1024,2048) | zqw floats [2048,2112)
    float* sCw = &sC[w * 16 * SCW];
    int*   cbw = (int*)sCw;
    float* vbw = sCw + 1024;
    float* zqw = sCw + 2048;
    zqw[lane] = z_loc;
    #pragma unroll
    for (int k = 0; k < TOPK; k++) {
        vbw[lane * 16 + k] = tv[k];
        cbw[lane * 16 + k] = tc16[k];
    }
    if (q == 0) {
        float Z = zqw[lane] + zqw[lane + 1] + zqw[lane + 2] + zqw[lane + 3];
        float lz = logf(Z);
        const int grow = s0 + w * 16 + sr;
        rzbuf[b * N_ + grow] = 1.0f / Z;
        tmin = -1e30f; tminslot = 0; tmincol = 0x7fffffff;
        #pragma unroll
        for (int k = 0; k < TOPK; k++) { tv[k] = -1e30f; tc16[k] = 0x7fffffff; }
        for (int qq = 0; qq < 4; qq++) {
            #pragma unroll 1
            for (int k = 0; k < TOPK; k++) {
                float v = vbw[(lane + qq) * 16 + k];
                int c = cbw[(lane + qq) * 16 + k];
                bool ins = (v > tmin) || (v == tmin && c < tmincol);
                if (ins) {
                    #pragma unroll
                    for (int k2 = 0; k2 < TOPK; k2++)
                        if (k2 == tminslot) { tv[k2] = v; tc16[k2] = c; }
                    tmin = tv[0]; tmincol = tc16[0]; tminslot = 0;
                    #pragma unroll
                    for (int k2 = 1; k2 < TOPK; k2++) {
                        bool worse = (tv[k2] < tmin) || (tv[k2] == tmin && tc16[k2] > tmincol);
                        if (worse) { tmin = tv[k2]; tmincol = tc16[k2]; tminslot = k2; }
                    }
                }
            }
        }
        unsigned used = 0;
        size_t rowbase = ((size_t)b * N_ + grow) * TOPK;
        for (int o = 0; o < TOPK; o++) {
            float bvv = -1e31f; int bcc = 0x7fffffff; int bk = 0;
            #pragma unroll
            for (int k = 0; k < TOPK; k++) {
                bool u = (used >> k) & 1u;
                bool better = !u && ((tv[k] > bvv) || (tv[k] == bvv && tc16[k] < bcc));
                if (better) { bvv = tv[k]; bcc = tc16[k]; bk = k; }
            }
            used |= 1u << bk;
            topv[rowbase + o] = bvv - lz;
            topc[rowbase + o] = bcc;
        }
    }
}

// ---------------------------------------------------------------------------
// Pass 2: same GEMM; colsum[b][t] += sum_s exp(l[s][t])*rz[s].
// Grid 512 (2-way col split), 512 threads; register-only epilogue + atomics.
// ---------------------------------------------------------------------------
__global__ __launch_bounds__(512, 2) void gemm8(
    const u16* __restrict__ srcP, const u16* __restrict__ tgtP,
    const float* __restrict__ rzbuf, float* __restrict__ colsum)
{
    __shared__ __align__(16) u16 sS[2 * 16384];
    __shared__ float sRZ[128];

    const int tid = threadIdx.x;
    const int w = tid >> 6, lane = tid & 63;
    const int wr = w >> 2, wc = w & 3;
    const int bid = blockIdx.x;
    const int swz = (bid & 7) * 64 + (bid >> 3);     // 8 XCD * 64; 2 batches/XCD
    const int b   = swz >> 5;
    const int rb  = swz & 31;
    const int s0  = (rb & 15) * 128;
    const int cb0 = (rb >> 4) * 1024;
    const float scale = 0.044194173824159216f;

    const u16* srcPb = srcP + (size_t)b * N_ * KP;
    const u16* tgtPb = tgtP + (size_t)b * N_ * KP;

    if (tid < 128) sRZ[tid] = rzbuf[b * N_ + s0 + tid];  // ordered by first barrier

    const int sls = ((lane & 3) ^ ((lane >> 3) & 3)) * 8;
    const u16* pAh = srcPb + (size_t)(s0 + w * 16 + (lane >> 2)) * KP + sls;
    const u16* pB  = tgtPb + (size_t)(w * 16 + (lane >> 2)) * KP + sls;
    const int aro = (lane & 15) * BK + (((lane >> 4) ^ ((lane >> 1) & 3)) * 8);

    auto stage = [&](int bi, int s, int c0) {
        u16* base = &sS[bi * 16384];
        const int t32 = (s & 15) * BK;
        gl_lds16(pAh + t32, base + w * 512);
        if (s < 16) {
            gl_lds16(pAh + 512 + t32, base + 4096 + w * 512);
            gl_lds16(pB + (size_t)c0 * KP + t32,         base + 8192 + w * 512);
            gl_lds16(pB + (size_t)(c0 + 128) * KP + t32, base + 12288 + w * 512);
        } else {
            gl_lds16(pB + (size_t)c0 * KP + 512 + t32,         base + 8192 + w * 512);
            gl_lds16(pB + (size_t)(c0 + 128) * KP + 512 + t32, base + 12288 + w * 512);
        }
    };

    stage(0, 0, cb0);

    for (int ch = 0; ch < 4; ch++) {
        const int c0 = cb0 + ch * BN7;
        f32x4 acc[4][4];
        #pragma unroll
        for (int i = 0; i < 4; i++)
            #pragma unroll
            for (int j = 0; j < 4; j++) acc[i][j] = (f32x4){0.f, 0.f, 0.f, 0.f};

        for (int s = 0; s < 32; s++) {
            __syncthreads();
            if (s < 31)      stage((s + 1) & 1, s + 1, c0);
            else if (ch < 3) stage(0, 0, c0 + BN7);
            const u16* base = &sS[(s & 1) * 16384];
            bf16x8 afr[4], bfr[4];
            #pragma unroll
            for (int j = 0; j < 4; j++)
                bfr[j] = *(const bf16x8*)&base[8192 + wc * 2048 + j * 512 + aro];
            #pragma unroll
            for (int i = 0; i < 4; i++)
                afr[i] = *(const bf16x8*)&base[wr * 2048 + i * 512 + aro];
            #pragma unroll
            for (int i = 0; i < 4; i++)
                #pragma unroll
                for (int j = 0; j < 4; j++)
                    acc[i][j] = __builtin_amdgcn_mfma_f32_16x16x32_bf16(
                        afr[i], bfr[j], acc[i][j], 0, 0, 0);
            if (s < 16) {
                #pragma unroll
                for (int i = 0; i < 4; i++)
                    afr[i] = *(const bf16x8*)&base[4096 + wr * 2048 + i * 512 + aro];
                #pragma unroll
                for (int i = 0; i < 4; i++)
                    #pragma unroll
                    for (int j = 0; j < 4; j++)
                        acc[i][j] = __builtin_amdgcn_mfma_f32_16x16x32_bf16(
                            afr[i], bfr[j], acc[i][j], 0, 0, 0);
            }
        }

        // register-only epilogue: lane holds col wc*64+j*16+(lane&15),
        // rows wr*64 + i*16 + (lane>>4)*4 + r
        #pragma unroll
        for (int j = 0; j < 4; j++) {
            float s = 0.f;
            #pragma unroll
            for (int i = 0; i < 4; i++)
                #pragma unroll
                for (int r = 0; r < 4; r++)
                    s += expf(acc[i][j][r] * scale)
                         * sRZ[wr * 64 + i * 16 + (lane >> 4) * 4 + r];
            s += __shfl_xor(s, 16);
            s += __shfl_xor(s, 32);
            if (lane < 16)
                atomicAdd(&colsum[b * N_ + c0 + wc * 64 + j * 16 + lane], s);
        }
    }
}

// ---------------------------------------------------------------------------
// Greedy match: per-row current-best + rescan on collision. 1 block/batch.
// ---------------------------------------------------------------------------
__global__ __launch_bounds__(256) void match2(
    const float* __restrict__ topv, const int* __restrict__ topc,
    int* __restrict__ mrow, int* __restrict__ mcol)
{
    const int b = blockIdx.x, tid = threadIdx.x;
    __shared__ float bv[N_];
    __shared__ int bc[N_];
    __shared__ int sup[16];
    __shared__ float rv[256];
    __shared__ int rr[256];

    for (int r = tid; r < N_; r += 256) {
        bv[r] = topv[((size_t)b * N_ + r) * TOPK];
        bc[r] = topc[((size_t)b * N_ + r) * TOPK];
    }
    __syncthreads();

    for (int it = 0; it < S_; it++) {
        float mv = -1e30f; int mr = 0x7fffffff;
        #pragma unroll
        for (int j = 0; j < 8; j++) {
            int r = tid + j * 256;
            float v = bv[r];
            if (v > mv) { mv = v; mr = r; }
        }
        rv[tid] = mv; rr[tid] = mr;
        __syncthreads();
        for (int off = 128; off; off >>= 1) {
            if (tid < off) {
                float v2 = rv[tid + off];
                if (v2 > rv[tid] || (v2 == rv[tid] && rr[tid + off] < rr[tid])) {
                    rv[tid] = v2; rr[tid] = rr[tid + off];
                }
            }
            __syncthreads();
        }
        if (tid == 0) {
            int R = rr[0]; int C = bc[R];
            mrow[b * S_ + it] = R; mcol[b * S_ + it] = C;
            sup[it] = C;
            bv[R] = -1e30f;
        }
        __syncthreads();
        const int C = sup[it];
        for (int r = tid; r < N_; r += 256) {
            if (bc[r] == C && bv[r] > -1e29f) {
                float nv = -1e30f; int nc = 0x7fffffff;
                const float* tvp = &topv[((size_t)b * N_ + r) * TOPK];
                const int* tcp = &topc[((size_t)b * N_ + r) * TOPK];
                for (int k = 0; k < TOPK; k++) {
                    int c2 = tcp[k];
                    bool bad = false;
                    for (int qq = 0; qq <= it; qq++) bad = bad || (sup[qq] == c2);
                    if (!bad) { nv = tvp[k]; nc = c2; break; }
                }
                bv[r] = nv; bc[r] = nc;
            }
        }
        __syncthreads();
    }
}

// ---------------------------------------------------------------------------
// Final: means, Kabsch (3x3 Jacobi SVD in fp64), R and t. One block per batch.
// ---------------------------------------------------------------------------
__global__ void finish_kernel(const float* __restrict__ src,
                              const float* __restrict__ tgt,
                              const float* __restrict__ colsum,
                              const int* __restrict__ mrow,
                              const int* __restrict__ mcol,
                              float* __restrict__ out)
{
    const int b = blockIdx.x;
    const int tid = threadIdx.x;
    __shared__ float red[256];
    __shared__ float res[6];

    float ls[3] = {0, 0, 0}, lc[3] = {0, 0, 0};
    for (int n = tid; n < N_; n += 256) {
        float cs = colsum[b * N_ + n];
        #pragma unroll
        for (int j = 0; j < 3; j++) {
            ls[j] += src[(size_t)(b * N_ + n) * 3 + j];
            lc[j] += tgt[(size_t)(b * N_ + n) * 3 + j] * cs;
        }
    }
    for (int j = 0; j < 6; j++) {
        red[tid] = (j < 3) ? ls[j] : lc[j - 3];
        __syncthreads();
        for (int off = 128; off; off >>= 1) {
            if (tid < off) red[tid] += red[tid + off];
            __syncthreads();
        }
        if (tid == 0) res[j] = red[0] / (float)N_;
        __syncthreads();
    }

    if (tid == 0) {
        double ps[S_][3], pt[S_][3];
        double ms[3] = {0, 0, 0}, mt[3] = {0, 0, 0};
        for (int s = 0; s < S_; s++) {
            int r = mrow[b * S_ + s], c = mcol[b * S_ + s];
            for (int j = 0; j < 3; j++) {
                ps[s][j] = (double)src[(size_t)(b * N_ + r) * 3 + j];
                pt[s][j] = (double)tgt[(size_t)(b * N_ + c) * 3 + j];
                ms[j] += ps[s][j]; mt[j] += pt[s][j];
            }
        }
        for (int j = 0; j < 3; j++) { ms[j] /= S_; mt[j] /= S_; }
        double H[3][3] = {{0,0,0},{0,0,0},{0,0,0}};
        for (int s = 0; s < S_; s++)
            for (int i = 0; i < 3; i++)
                for (int j = 0; j < 3; j++)
                    H[i][j] += (ps[s][i] - ms[i]) * (pt[s][j] - mt[j]);

        double A[3][3], Vv[3][3] = {{1,0,0},{0,1,0},{0,0,1}};
        for (int i = 0; i < 3; i++)
            for (int j = 0; j < 3; j++) {
                double acc = 0;
                for (int k = 0; k < 3; k++) acc += H[k][i] * H[k][j];
                A[i][j] = acc;
            }
        for (int sweep = 0; sweep < 30; sweep++) {
            double off = fabs(A[0][1]) + fabs(A[0][2]) + fabs(A[1][2]);
            if (off < 1e-30) break;
            for (int pair = 0; pair < 3; pair++) {
                int p = (pair == 2) ? 1 : 0;
                int q = (pair == 0) ? 1 : 2;
                double apq = A[p][q];
                if (fabs(apq) < 1e-300) continue;
                double theta = (A[q][q] - A[p][p]) / (2.0 * apq);
                double tt = ((theta >= 0) ? 1.0 : -1.0) / (fabs(theta) + sqrt(theta * theta + 1.0));
                double cc = 1.0 / sqrt(tt * tt + 1.0);
                double ssn = tt * cc;
                for (int k = 0; k < 3; k++) {
                    double akp = A[k][p], akq = A[k][q];
                    A[k][p] = cc * akp - ssn * akq;
                    A[k][q] = ssn * akp + cc * akq;
                }
                for (int k = 0; k < 3; k++) {
                    double apk = A[p][k], aqk = A[q][k];
                    A[p][k] = cc * apk - ssn * aqk;
                    A[q][k] = ssn * apk + cc * aqk;
                }
                for (int k = 0; k < 3; k++) {
                    double vkp = Vv[k][p], vkq = Vv[k][q];
                    Vv[k][p] = cc * vkp - ssn * vkq;
                    Vv[k][q] = ssn * vkp + cc * vkq;
                }
            }
        }
        double wv[3] = {A[0][0], A[1][1], A[2][2]};
        for (int a = 0; a < 2; a++)
            for (int b2 = a + 1; b2 < 3; b2++)
                if (wv[b2] > wv[a]) {
                    double tw = wv[a]; wv[a] = wv[b2]; wv[b2] = tw;
                    for (int k = 0; k < 3; k++) {
                        double tv_ = Vv[k][a]; Vv[k][a] = Vv[k][b2]; Vv[k][b2] = tv_;
                    }
                }
        double U[3][3];
        for (int k = 0; k < 3; k++) {
            double u[3], nrm = 0;
            for (int i = 0; i < 3; i++) {
                double acc = 0;
                for (int j = 0; j < 3; j++) acc += H[i][j] * Vv[j][k];
                u[i] = acc; nrm += acc * acc;
            }
            nrm = sqrt(nrm);
            if (nrm < 1e-300) nrm = 1e-300;
            for (int i = 0; i < 3; i++) U[i][k] = u[i] / nrm;
        }
        double r[3][3];
        for (int i = 0; i < 3; i++)
            for (int j = 0; j < 3; j++) {
                double acc = 0;
                for (int k = 0; k < 3; k++) acc += Vv[i][k] * U[j][k];
                r[i][j] = acc;
            }
        double det = r[0][0] * (r[1][1] * r[2][2] - r[1][2] * r[2][1])
                   - r[0][1] * (r[1][0] * r[2][2] - r[1][2] * r[2][0])
                   + r[0][2] * (r[1][0] * r[2][1] - r[1][1] * r[2][0]);
        if (det < 0.0) {
            for (int i = 0; i < 3; i++)
                for (int j = 0; j < 3; j++)
                    r[i][j] -= 2.0 * Vv[i][2] * U[j][2];
        }
        double smean[3] = {(double)res[0], (double)res[1], (double)res[2]};
        double cmean[3] = {(double)res[3], (double)res[4], (double)res[5]};
        for (int i = 0; i < 3; i++)
            for (int j = 0; j < 3; j++)
                out[b * 9 + i * 3 + j] = (float)r[i][j];
        for (int i = 0; i < 3; i++) {
            double acc = cmean[i];
            for (int j = 0; j < 3; j++) acc -= r[i][j] * smean[j];
            out[B_ * 9 + b * 3 + i] = (float)acc;
        }
    }
}

// ---------------------------------------------------------------------------
extern "C" void kernel_launch(void* const* d_in, const int* in_sizes, int n_in,
                              void* d_out, int out_size, void* d_ws, size_t ws_size,
                              hipStream_t stream)
{
    const float* srcE = (const float*)d_in[0];
    const float* tgtE = (const float*)d_in[1];
    const float* src  = (const float*)d_in[2];
    const float* tgt  = (const float*)d_in[3];
    float* out = (float*)d_out;
    char* ws = (char*)d_ws;

    // workspace: 128 MiB packed + 4.25 MiB stats = 132.25 MiB (proven size)
    const size_t szP = (size_t)B_ * N_ * KP * sizeof(u16);      // 64 MiB each
    u16* srcP = (u16*)ws;
    u16* tgtP = (u16*)(ws + szP);
    size_t off = 2 * szP;
    float* rzbuf  = (float*)(ws + off); off += (size_t)B_ * N_ * sizeof(float);
    float* topv   = (float*)(ws + off); off += (size_t)B_ * N_ * TOPK * sizeof(float);
    int*   topc   = (int*)(ws + off);   off += (size_t)B_ * N_ * TOPK * sizeof(int);
    float* colsum = (float*)(ws + off); off += (size_t)B_ * N_ * sizeof(float);
    int*   mrow   = (int*)(ws + off);   off += 1024;
    int*   mcol   = (int*)(ws + off);

    hipMemsetAsync(colsum, 0, (size_t)B_ * N_ * sizeof(float), stream);

    packbf<<<dim3(N_ / 64, D_ / 64, 2 * B_), 256, 0, stream>>>(srcE, tgtE, srcP, tgtP);
    gemm7<<<dim3(256), 512, 0, stream>>>(srcP, tgtP, rzbuf, topv, topc);
    gemm8<<<dim3(512), 512, 0, stream>>>(srcP, tgtP, rzbuf, colsum);
    match2<<<B_, 256, 0, stream>>>(topv, topc, mrow, mcol);
    finish_kernel<<<B_, 256, 0, stream>>>(src, tgt, colsum, mrow, mcol, out);
}

// Round 4
// 711.999 us; speedup vs baseline: 2.3544x; 1.7103x over previous
//
#include <hip/hip_runtime.h>
#include <hip/hip_fp16.h>
#include <math.h>

typedef unsigned short u16;
typedef __attribute__((ext_vector_type(8))) short bf16x8;   // 8 bf16 = 4 VGPR
typedef __attribute__((ext_vector_type(4))) float f32x4;

constexpr int B_ = 16;
constexpr int D_ = 512;
constexpr int N_ = 2048;
constexpr int S_ = 15;
constexpr int TOPK = 16;

constexpr int BK  = 32;
constexpr int KP  = 2 * D_;           // 1024 packed bf16 per row (hi|lo)
constexpr int SCW = 132;              // sC row stride (128 + 4 pad)
constexpr int BN7 = 256;              // chunk width
constexpr int NCH7 = N_ / BN7;        // 8

// async global->LDS, 16 bytes per lane (dest = wave-uniform base + lane*16)
__device__ __forceinline__ void gl_lds16(const void* g, void* s) {
    __builtin_amdgcn_global_load_lds(
        (const __attribute__((address_space(1))) unsigned int*)g,
        (__attribute__((address_space(3))) unsigned int*)s, 16, 0, 0);
}

// fp8 e4m3fn encode of a POSITIVE float (we only encode exp(l) > 0).
// flush <2^-6 to 0 (tail contribution negligible), saturate at 448, rn-even.
__device__ __forceinline__ unsigned enc1(float x) {
    x = fminf(x, 448.f);
    unsigned u = __float_as_uint(x);
    if (u < 0x3C800000u) return 0u;                    // < 2^-6
    unsigned r = u + 0x7FFFFu + ((u >> 20) & 1u);      // rn-even, keep 3 mant bits
    unsigned f = (r >> 20) - 0x3C0u;                   // rebias 127->7
    return f > 0x7Eu ? 0x7Eu : f;
}
__device__ __forceinline__ float dec1(unsigned f) {
    return f ? __uint_as_float((f + 0x3C0u) << 20) : 0.f;
}

// ---------------------------------------------------------------------------
// Pack: fp32 [B][D][N] -> bf16 [B][N][1024] N-major, row = [hi(0..511)|lo].
// ---------------------------------------------------------------------------
__global__ __launch_bounds__(256) void packbf(
    const float* __restrict__ srcE, const float* __restrict__ tgtE,
    u16* __restrict__ srcP, u16* __restrict__ tgtP)
{
    const int t = threadIdx.x;
    const int b = blockIdx.z & 15, sel = blockIdx.z >> 4;
    const float* in = (sel ? tgtE : srcE) + (size_t)b * D_ * N_;
    u16* out = (sel ? tgtP : srcP) + (size_t)b * N_ * KP;
    const int n0 = blockIdx.x * 64, k0 = blockIdx.y * 64;

    __shared__ float T[64][69];

    #pragma unroll
    for (int it = 0; it < 4; it++) {
        int r = it * 16 + (t >> 4);
        int c = (t & 15) * 4;
        float4 v = *(const float4*)&in[(size_t)(k0 + r) * N_ + n0 + c];
        T[c + 0][r] = v.x; T[c + 1][r] = v.y; T[c + 2][r] = v.z; T[c + 3][r] = v.w;
    }
    __syncthreads();

    const int nn = t >> 2, kc = (t & 3) * 16;
    __align__(16) u16 hi[16], lo[16];
    #pragma unroll
    for (int j = 0; j < 16; j++) {
        float x = T[nn][kc + j];
        unsigned u = __float_as_uint(x);
        unsigned hr = u + 0x7fff + ((u >> 16) & 1);
        u16 h = (u16)(hr >> 16);
        float hf = __uint_as_float((unsigned)h << 16);
        float xl = x - hf;
        unsigned ul = __float_as_uint(xl);
        unsigned lr = ul + 0x7fff + ((ul >> 16) & 1);
        hi[j] = h; lo[j] = (u16)(lr >> 16);
    }
    u16* op = out + (size_t)(n0 + nn) * KP + k0 + kc;
    *(int4*)op         = *(int4*)hi;  *(int4*)(op + 8)   = *(int4*)(hi + 8);
    *(int4*)(op + 512) = *(int4*)lo;  *(int4*)(op + 520) = *(int4*)(lo + 8);
}

// ---------------------------------------------------------------------------
// Pass 1: MFMA GEMM -> 1/Z + sorted top-16 (l - logZ), optional fp8 E dump.
// Grid 256 (16 rowblocks x 16 batches, XCD-chunked), 512 threads.
// ---------------------------------------------------------------------------
__global__ __launch_bounds__(512, 2) void gemm7(
    const u16* __restrict__ srcP, const u16* __restrict__ tgtP,
    float* __restrict__ rzbuf, float* __restrict__ topv, int* __restrict__ topc,
    unsigned char* __restrict__ e8)       // nullptr -> no dump (thin path)
{
    __shared__ __align__(16) u16 sS[2 * 16384];      // 64 KB staging
    __shared__ __align__(16) float sC[128 * SCW];    // 67.6 KB epilogue

    const int tid = threadIdx.x;
    const int w = tid >> 6, lane = tid & 63;
    const int wr = w >> 2, wc = w & 3;
    const int sr = lane >> 2, q = lane & 3;
    const int bid = blockIdx.x;
    const int swz = (bid & 7) * 32 + (bid >> 3);
    const int b  = swz >> 4;
    const int s0 = (swz & 15) * 128;
    const float scale = 0.044194173824159216f;

    const u16* srcPb = srcP + (size_t)b * N_ * KP;
    const u16* tgtPb = tgtP + (size_t)b * N_ * KP;

    const int sls = ((lane & 3) ^ ((lane >> 3) & 3)) * 8;
    const u16* pAh = srcPb + (size_t)(s0 + w * 16 + (lane >> 2)) * KP + sls;
    const u16* pB  = tgtPb + (size_t)(w * 16 + (lane >> 2)) * KP + sls;
    const int aro = (lane & 15) * BK + (((lane >> 4) ^ ((lane >> 1) & 3)) * 8);

    auto stage = [&](int bi, int s, int c0) {
        u16* base = &sS[bi * 16384];
        const int t32 = (s & 15) * BK;
        gl_lds16(pAh + t32, base + w * 512);                          // Ah
        if (s < 16) {
            gl_lds16(pAh + 512 + t32, base + 4096 + w * 512);         // Al
            gl_lds16(pB + (size_t)c0 * KP + t32,         base + 8192 + w * 512);
            gl_lds16(pB + (size_t)(c0 + 128) * KP + t32, base + 12288 + w * 512);
        } else {
            gl_lds16(pB + (size_t)c0 * KP + 512 + t32,         base + 8192 + w * 512);
            gl_lds16(pB + (size_t)(c0 + 128) * KP + 512 + t32, base + 12288 + w * 512);
        }
    };

    float z_loc = 0.f;
    float tv[TOPK]; int tc16[TOPK];
    #pragma unroll
    for (int k = 0; k < TOPK; k++) { tv[k] = -1e30f; tc16[k] = 0x7fffffff; }

    stage(0, 0, 0);

    for (int ch = 0; ch < NCH7; ch++) {
        const int c0 = ch * BN7;
        f32x4 acc[4][4];
        #pragma unroll
        for (int i = 0; i < 4; i++)
            #pragma unroll
            for (int j = 0; j < 4; j++) acc[i][j] = (f32x4){0.f, 0.f, 0.f, 0.f};

        for (int s = 0; s < 32; s++) {
            __syncthreads();
            if (s < 31)              stage((s + 1) & 1, s + 1, c0);
            else if (ch < NCH7 - 1)  stage(0, 0, c0 + BN7);
            const u16* base = &sS[(s & 1) * 16384];
            bf16x8 afr[4], bfr[4];
            #pragma unroll
            for (int j = 0; j < 4; j++)
                bfr[j] = *(const bf16x8*)&base[8192 + wc * 2048 + j * 512 + aro];
            #pragma unroll
            for (int i = 0; i < 4; i++)
                afr[i] = *(const bf16x8*)&base[wr * 2048 + i * 512 + aro];
            #pragma unroll
            for (int i = 0; i < 4; i++)
                #pragma unroll
                for (int j = 0; j < 4; j++)
                    acc[i][j] = __builtin_amdgcn_mfma_f32_16x16x32_bf16(
                        afr[i], bfr[j], acc[i][j], 0, 0, 0);
            if (s < 16) {
                #pragma unroll
                for (int i = 0; i < 4; i++)
                    afr[i] = *(const bf16x8*)&base[4096 + wr * 2048 + i * 512 + aro];
                #pragma unroll
                for (int i = 0; i < 4; i++)
                    #pragma unroll
                    for (int j = 0; j < 4; j++)
                        acc[i][j] = __builtin_amdgcn_mfma_f32_16x16x32_bf16(
                            afr[i], bfr[j], acc[i][j], 0, 0, 0);
            }
        }

        // ---- epilogue: 2 halves of 128 cols through sC.
        // Stats: lane (sr,q) owns row w*16+sr, contiguous cols [q*32, q*32+32)
        // of the half (ascending col stream per lane -> stable tie-break with
        // strict >). exp() computed once; reused for fp8 dump.
        #pragma unroll 1
        for (int h = 0; h < 2; h++) {
            __syncthreads();
            if ((wc >> 1) == h) {
                const int cb = (wc & 1) * 64;
                #pragma unroll
                for (int i = 0; i < 4; i++)
                    #pragma unroll
                    for (int j = 0; j < 4; j++)
                        #pragma unroll
                        for (int r = 0; r < 4; r++)
                            sC[(wr * 64 + i * 16 + (lane >> 4) * 4 + r) * SCW
                               + cb + j * 16 + (lane & 15)] = acc[i][j][r] * scale;
            }
            __syncthreads();
            const float* rowp = &sC[(w * 16 + sr) * SCW + q * 32];
            const int cbase = c0 + h * 128 + q * 32;
            const size_t erow = ((size_t)(b * N_ + s0 + w * 16 + sr)) * N_
                                + c0 + h * 128 + q * 32;
            #pragma unroll 1
            for (int mo = 0; mo < 2; mo++) {
                unsigned ow0 = 0, ow1 = 0, ow2 = 0, ow3 = 0;
                #pragma unroll
                for (int mi = 0; mi < 4; mi++) {
                    float4 v4 = *(const float4*)&rowp[mo * 16 + mi * 4];
                    const float vv[4] = {v4.x, v4.y, v4.z, v4.w};
                    unsigned wb = 0;
                    #pragma unroll
                    for (int e = 0; e < 4; e++) {
                        float v = vv[e];
                        float ex = __expf(v);
                        z_loc += ex;
                        wb |= enc1(ex) << (8 * e);
                        if (v > tv[15]) {       // sorted-desc insert, stable
                            const int c = cbase + mo * 16 + mi * 4 + e;
                            #pragma unroll
                            for (int k = 15; k >= 1; k--) {
                                bool bk  = v > tv[k];
                                bool bk1 = v > tv[k - 1];
                                float sv = bk1 ? tv[k - 1] : v;
                                int   sc = bk1 ? tc16[k - 1] : c;
                                tv[k]   = bk ? sv : tv[k];
                                tc16[k] = bk ? sc : tc16[k];
                            }
                            if (v > tv[0]) { tv[0] = v; tc16[0] = c; }
                        }
                    }
                    if (mi == 0) ow0 = wb; else if (mi == 1) ow1 = wb;
                    else if (mi == 2) ow2 = wb; else ow3 = wb;
                }
                if (e8) *(uint4*)&e8[erow + mo * 16] = make_uint4(ow0, ow1, ow2, ow3);
            }
        }
    }

    // ---- final merge: wave-private inside own 16-row sC slice ----
    float* sCw = &sC[w * 16 * SCW];
    int*   cbw = (int*)sCw;
    float* vbw = sCw + 1024;
    float* zqw = sCw + 2048;
    zqw[lane] = z_loc;
    #pragma unroll
    for (int k = 0; k < TOPK; k++) {
        vbw[lane * 16 + k] = tv[k];
        cbw[lane * 16 + k] = tc16[k];
    }
    if (q == 0) {
        float Z = zqw[lane] + zqw[lane + 1] + zqw[lane + 2] + zqw[lane + 3];
        float lz = logf(Z);
        const int grow = s0 + w * 16 + sr;
        rzbuf[b * N_ + grow] = 1.0f / Z;
        float tmin = -1e30f; int tminslot = 0, tmincol = 0x7fffffff;
        #pragma unroll
        for (int k = 0; k < TOPK; k++) { tv[k] = -1e30f; tc16[k] = 0x7fffffff; }
        for (int qq = 0; qq < 4; qq++) {
            #pragma unroll 1
            for (int k = 0; k < TOPK; k++) {
                float v = vbw[(lane + qq) * 16 + k];
                int c = cbw[(lane + qq) * 16 + k];
                bool ins = (v > tmin) || (v == tmin && c < tmincol);
                if (ins) {
                    #pragma unroll
                    for (int k2 = 0; k2 < TOPK; k2++)
                        if (k2 == tminslot) { tv[k2] = v; tc16[k2] = c; }
                    tmin = tv[0]; tmincol = tc16[0]; tminslot = 0;
                    #pragma unroll
                    for (int k2 = 1; k2 < TOPK; k2++) {
                        bool worse = (tv[k2] < tmin) || (tv[k2] == tmin && tc16[k2] > tmincol);
                        if (worse) { tmin = tv[k2]; tmincol = tc16[k2]; tminslot = k2; }
                    }
                }
            }
        }
        unsigned used = 0;
        size_t rowbase = ((size_t)b * N_ + grow) * TOPK;
        for (int o = 0; o < TOPK; o++) {
            float bvv = -1e31f; int bcc = 0x7fffffff; int bk = 0;
            #pragma unroll
            for (int k = 0; k < TOPK; k++) {
                bool u = (used >> k) & 1u;
                bool better = !u && ((tv[k] > bvv) || (tv[k] == bvv && tc16[k] < bcc));
                if (better) { bvv = tv[k]; bcc = tc16[k]; bk = k; }
            }
            used |= 1u << bk;
            topv[rowbase + o] = bvv - lz;
            topc[rowbase + o] = bcc;
        }
    }
}

// ---------------------------------------------------------------------------
// Fat path: colsum[b][t] = sum_s dec(E8[s][t]) * rz[s]. Grid (2,16,16), 256 thr.
// ---------------------------------------------------------------------------
__global__ __launch_bounds__(256) void colsum3(
    const unsigned char* __restrict__ e8, const float* __restrict__ rzbuf,
    float* __restrict__ colsum)
{
    const int b = blockIdx.z, s0 = blockIdx.y * 128, t0 = blockIdx.x * 1024;
    __shared__ float srz[128];
    if (threadIdx.x < 128) srz[threadIdx.x] = rzbuf[b * N_ + s0 + threadIdx.x];
    __syncthreads();
    const int t = t0 + threadIdx.x * 4;
    const unsigned char* p = e8 + ((size_t)(b * N_ + s0)) * N_ + t;
    float a0 = 0.f, a1 = 0.f, a2 = 0.f, a3 = 0.f;
    #pragma unroll 4
    for (int s = 0; s < 128; s++) {
        unsigned v = *(const unsigned*)(p + (size_t)s * N_);
        float r = srz[s];
        a0 += dec1(v & 255u) * r;
        a1 += dec1((v >> 8) & 255u) * r;
        a2 += dec1((v >> 16) & 255u) * r;
        a3 += dec1(v >> 24) * r;
    }
    atomicAdd(&colsum[b * N_ + t + 0], a0);
    atomicAdd(&colsum[b * N_ + t + 1], a1);
    atomicAdd(&colsum[b * N_ + t + 2], a2);
    atomicAdd(&colsum[b * N_ + t + 3], a3);
}

// ---------------------------------------------------------------------------
// Thin fallback: recompute GEMM; colsum += sum_s exp(l)*rz. Grid 512, 512 thr.
// ---------------------------------------------------------------------------
__global__ __launch_bounds__(512, 2) void gemm8(
    const u16* __restrict__ srcP, const u16* __restrict__ tgtP,
    const float* __restrict__ rzbuf, float* __restrict__ colsum)
{
    __shared__ __align__(16) u16 sS[2 * 16384];
    __shared__ float sRZ[128];

    const int tid = threadIdx.x;
    const int w = tid >> 6, lane = tid & 63;
    const int wr = w >> 2, wc = w & 3;
    const int bid = blockIdx.x;
    const int swz = (bid & 7) * 64 + (bid >> 3);
    const int b   = swz >> 5;
    const int rb  = swz & 31;
    const int s0  = (rb & 15) * 128;
    const int cb0 = (rb >> 4) * 1024;
    const float scale = 0.044194173824159216f;

    const u16* srcPb = srcP + (size_t)b * N_ * KP;
    const u16* tgtPb = tgtP + (size_t)b * N_ * KP;

    if (tid < 128) sRZ[tid] = rzbuf[b * N_ + s0 + tid];

    const int sls = ((lane & 3) ^ ((lane >> 3) & 3)) * 8;
    const u16* pAh = srcPb + (size_t)(s0 + w * 16 + (lane >> 2)) * KP + sls;
    const u16* pB  = tgtPb + (size_t)(w * 16 + (lane >> 2)) * KP + sls;
    const int aro = (lane & 15) * BK + (((lane >> 4) ^ ((lane >> 1) & 3)) * 8);

    auto stage = [&](int bi, int s, int c0) {
        u16* base = &sS[bi * 16384];
        const int t32 = (s & 15) * BK;
        gl_lds16(pAh + t32, base + w * 512);
        if (s < 16) {
            gl_lds16(pAh + 512 + t32, base + 4096 + w * 512);
            gl_lds16(pB + (size_t)c0 * KP + t32,         base + 8192 + w * 512);
            gl_lds16(pB + (size_t)(c0 + 128) * KP + t32, base + 12288 + w * 512);
        } else {
            gl_lds16(pB + (size_t)c0 * KP + 512 + t32,         base + 8192 + w * 512);
            gl_lds16(pB + (size_t)(c0 + 128) * KP + 512 + t32, base + 12288 + w * 512);
        }
    };

    stage(0, 0, cb0);

    for (int ch = 0; ch < 4; ch++) {
        const int c0 = cb0 + ch * BN7;
        f32x4 acc[4][4];
        #pragma unroll
        for (int i = 0; i < 4; i++)
            #pragma unroll
            for (int j = 0; j < 4; j++) acc[i][j] = (f32x4){0.f, 0.f, 0.f, 0.f};

        for (int s = 0; s < 32; s++) {
            __syncthreads();
            if (s < 31)      stage((s + 1) & 1, s + 1, c0);
            else if (ch < 3) stage(0, 0, c0 + BN7);
            const u16* base = &sS[(s & 1) * 16384];
            bf16x8 afr[4], bfr[4];
            #pragma unroll
            for (int j = 0; j < 4; j++)
                bfr[j] = *(const bf16x8*)&base[8192 + wc * 2048 + j * 512 + aro];
            #pragma unroll
            for (int i = 0; i < 4; i++)
                afr[i] = *(const bf16x8*)&base[wr * 2048 + i * 512 + aro];
            #pragma unroll
            for (int i = 0; i < 4; i++)
                #pragma unroll
                for (int j = 0; j < 4; j++)
                    acc[i][j] = __builtin_amdgcn_mfma_f32_16x16x32_bf16(
                        afr[i], bfr[j], acc[i][j], 0, 0, 0);
            if (s < 16) {
                #pragma unroll
                for (int i = 0; i < 4; i++)
                    afr[i] = *(const bf16x8*)&base[4096 + wr * 2048 + i * 512 + aro];
                #pragma unroll
                for (int i = 0; i < 4; i++)
                    #pragma unroll
                    for (int j = 0; j < 4; j++)
                        acc[i][j] = __builtin_amdgcn_mfma_f32_16x16x32_bf16(
                            afr[i], bfr[j], acc[i][j], 0, 0, 0);
            }
        }

        #pragma unroll
        for (int j = 0; j < 4; j++) {
            float s = 0.f;
            #pragma unroll
            for (int i = 0; i < 4; i++)
                #pragma unroll
                for (int r = 0; r < 4; r++)
                    s += __expf(acc[i][j][r] * scale)
                         * sRZ[wr * 64 + i * 16 + (lane >> 4) * 4 + r];
            s += __shfl_xor(s, 16);
            s += __shfl_xor(s, 32);
            if (lane < 16)
                atomicAdd(&colsum[b * N_ + c0 + wc * 64 + j * 16 + lane], s);
        }
    }
}

// ---------------------------------------------------------------------------
// Greedy match + finish (unchanged)
// ---------------------------------------------------------------------------
__global__ __launch_bounds__(256) void match2(
    const float* __restrict__ topv, const int* __restrict__ topc,
    int* __restrict__ mrow, int* __restrict__ mcol)
{
    const int b = blockIdx.x, tid = threadIdx.x;
    __shared__ float bv[N_];
    __shared__ int bc[N_];
    __shared__ int sup[16];
    __shared__ float rv[256];
    __shared__ int rr[256];

    for (int r = tid; r < N_; r += 256) {
        bv[r] = topv[((size_t)b * N_ + r) * TOPK];
        bc[r] = topc[((size_t)b * N_ + r) * TOPK];
    }
    __syncthreads();

    for (int it = 0; it < S_; it++) {
        float mv = -1e30f; int mr = 0x7fffffff;
        #pragma unroll
        for (int j = 0; j < 8; j++) {
            int r = tid + j * 256;
            float v = bv[r];
            if (v > mv) { mv = v; mr = r; }
        }
        rv[tid] = mv; rr[tid] = mr;
        __syncthreads();
        for (int off = 128; off; off >>= 1) {
            if (tid < off) {
                float v2 = rv[tid + off];
                if (v2 > rv[tid] || (v2 == rv[tid] && rr[tid + off] < rr[tid])) {
                    rv[tid] = v2; rr[tid] = rr[tid + off];
                }
            }
            __syncthreads();
        }
        if (tid == 0) {
            int R = rr[0]; int C = bc[R];
            mrow[b * S_ + it] = R; mcol[b * S_ + it] = C;
            sup[it] = C;
            bv[R] = -1e30f;
        }
        __syncthreads();
        const int C = sup[it];
        for (int r = tid; r < N_; r += 256) {
            if (bc[r] == C && bv[r] > -1e29f) {
                float nv = -1e30f; int nc = 0x7fffffff;
                const float* tvp = &topv[((size_t)b * N_ + r) * TOPK];
                const int* tcp = &topc[((size_t)b * N_ + r) * TOPK];
                for (int k = 0; k < TOPK; k++) {
                    int c2 = tcp[k];
                    bool bad = false;
                    for (int qq = 0; qq <= it; qq++) bad = bad || (sup[qq] == c2);
                    if (!bad) { nv = tvp[k]; nc = c2; break; }
                }
                bv[r] = nv; bc[r] = nc;
            }
        }
        __syncthreads();
    }
}

__global__ void finish_kernel(const float* __restrict__ src,
                              const float* __restrict__ tgt,
                              const float* __restrict__ colsum,
                              const int* __restrict__ mrow,
                              const int* __restrict__ mcol,
                              float* __restrict__ out)
{
    const int b = blockIdx.x;
    const int tid = threadIdx.x;
    __shared__ float red[256];
    __shared__ float res[6];

    float ls[3] = {0, 0, 0}, lc[3] = {0, 0, 0};
    for (int n = tid; n < N_; n += 256) {
        float cs = colsum[b * N_ + n];
        #pragma unroll
        for (int j = 0; j < 3; j++) {
            ls[j] += src[(size_t)(b * N_ + n) * 3 + j];
            lc[j] += tgt[(size_t)(b * N_ + n) * 3 + j] * cs;
        }
    }
    for (int j = 0; j < 6; j++) {
        red[tid] = (j < 3) ? ls[j] : lc[j - 3];
        __syncthreads();
        for (int off = 128; off; off >>= 1) {
            if (tid < off) red[tid] += red[tid + off];
            __syncthreads();
        }
        if (tid == 0) res[j] = red[0] / (float)N_;
        __syncthreads();
    }

    if (tid == 0) {
        double ps[S_][3], pt[S_][3];
        double ms[3] = {0, 0, 0}, mt[3] = {0, 0, 0};
        for (int s = 0; s < S_; s++) {
            int r = mrow[b * S_ + s], c = mcol[b * S_ + s];
            for (int j = 0; j < 3; j++) {
                ps[s][j] = (double)src[(size_t)(b * N_ + r) * 3 + j];
                pt[s][j] = (double)tgt[(size_t)(b * N_ + c) * 3 + j];
                ms[j] += ps[s][j]; mt[j] += pt[s][j];
            }
        }
        for (int j = 0; j < 3; j++) { ms[j] /= S_; mt[j] /= S_; }
        double H[3][3] = {{0,0,0},{0,0,0},{0,0,0}};
        for (int s = 0; s < S_; s++)
            for (int i = 0; i < 3; i++)
                for (int j = 0; j < 3; j++)
                    H[i][j] += (ps[s][i] - ms[i]) * (pt[s][j] - mt[j]);

        double A[3][3], Vv[3][3] = {{1,0,0},{0,1,0},{0,0,1}};
        for (int i = 0; i < 3; i++)
            for (int j = 0; j < 3; j++) {
                double acc = 0;
                for (int k = 0; k < 3; k++) acc += H[k][i] * H[k][j];
                A[i][j] = acc;
            }
        for (int sweep = 0; sweep < 30; sweep++) {
            double off = fabs(A[0][1]) + fabs(A[0][2]) + fabs(A[1][2]);
            if (off < 1e-30) break;
            for (int pair = 0; pair < 3; pair++) {
                int p = (pair == 2) ? 1 : 0;
                int q = (pair == 0) ? 1 : 2;
                double apq = A[p][q];
                if (fabs(apq) < 1e-300) continue;
                double theta = (A[q][q] - A[p][p]) / (2.0 * apq);
                double tt = ((theta >= 0) ? 1.0 : -1.0) / (fabs(theta) + sqrt(theta * theta + 1.0));
                double cc = 1.0 / sqrt(tt * tt + 1.0);
                double ssn = tt * cc;
                for (int k = 0; k < 3; k++) {
                    double akp = A[k][p], akq = A[k][q];
                    A[k][p] = cc * akp - ssn * akq;
                    A[k][q] = ssn * akp + cc * akq;
                }
                for (int k = 0; k < 3; k++) {
                    double apk = A[p][k], aqk = A[q][k];
                    A[p][k] = cc * apk - ssn * aqk;
                    A[q][k] = ssn * apk + cc * aqk;
                }
                for (int k = 0; k < 3; k++) {
                    double vkp = Vv[k][p], vkq = Vv[k][q];
                    Vv[k][p] = cc * vkp - ssn * vkq;
                    Vv[k][q] = ssn * vkp + cc * vkq;
                }
            }
        }
        double wv[3] = {A[0][0], A[1][1], A[2][2]};
        for (int a = 0; a < 2; a++)
            for (int b2 = a + 1; b2 < 3; b2++)
                if (wv[b2] > wv[a]) {
                    double tw = wv[a]; wv[a] = wv[b2]; wv[b2] = tw;
                    for (int k = 0; k < 3; k++) {
                        double tv_ = Vv[k][a]; Vv[k][a] = Vv[k][b2]; Vv[k][b2] = tv_;
                    }
                }
        double U[3][3];
        for (int k = 0; k < 3; k++) {
            double u[3], nrm = 0;
            for (int i = 0; i < 3; i++) {
                double acc = 0;
                for (int j = 0; j < 3; j++) acc += H[i][j] * Vv[j][k];
                u[i] = acc; nrm += acc * acc;
            }
            nrm = sqrt(nrm);
            if (nrm < 1e-300) nrm = 1e-300;
            for (int i = 0; i < 3; i++) U[i][k] = u[i] / nrm;
        }
        double r[3][3];
        for (int i = 0; i < 3; i++)
            for (int j = 0; j < 3; j++) {
                double acc = 0;
                for (int k = 0; k < 3; k++) acc += Vv[i][k] * U[j][k];
                r[i][j] = acc;
            }
        double det = r[0][0] * (r[1][1] * r[2][2] - r[1][2] * r[2][1])
                   - r[0][1] * (r[1][0] * r[2][2] - r[1][2] * r[2][0])
                   + r[0][2] * (r[1][0] * r[2][1] - r[1][1] * r[2][0]);
        if (det < 0.0) {
            for (int i = 0; i < 3; i++)
                for (int j = 0; j < 3; j++)
                    r[i][j] -= 2.0 * Vv[i][2] * U[j][2];
        }
        double smean[3] = {(double)res[0], (double)res[1], (double)res[2]};
        double cmean[3] = {(double)res[3], (double)res[4], (double)res[5]};
        for (int i = 0; i < 3; i++)
            for (int j = 0; j < 3; j++)
                out[b * 9 + i * 3 + j] = (float)r[i][j];
        for (int i = 0; i < 3; i++) {
            double acc = cmean[i];
            for (int j = 0; j < 3; j++) acc -= r[i][j] * smean[j];
            out[B_ * 9 + b * 3 + i] = (float)acc;
        }
    }
}

// ---------------------------------------------------------------------------
extern "C" void kernel_launch(void* const* d_in, const int* in_sizes, int n_in,
                              void* d_out, int out_size, void* d_ws, size_t ws_size,
                              hipStream_t stream)
{
    const float* srcE = (const float*)d_in[0];
    const float* tgtE = (const float*)d_in[1];
    const float* src  = (const float*)d_in[2];
    const float* tgt  = (const float*)d_in[3];
    float* out = (float*)d_out;
    char* ws = (char*)d_ws;

    const size_t szP  = (size_t)B_ * N_ * KP * sizeof(u16);   // 64 MiB each
    const size_t szE8 = (size_t)B_ * N_ * N_;                 // 64 MiB fp8
    const size_t szStats = (size_t)B_ * N_ * sizeof(float)              // rz
                         + (size_t)B_ * N_ * TOPK * sizeof(float)       // topv
                         + (size_t)B_ * N_ * TOPK * sizeof(int)         // topc
                         + (size_t)B_ * N_ * sizeof(float)              // colsum
                         + 2048;                                        // mrow/mcol
    const bool fat = ws_size >= 2 * szP + szE8 + szStats;     // 196.3 MiB

    u16* srcP = (u16*)ws;
    u16* tgtP = (u16*)(ws + szP);
    unsigned char* e8 = fat ? (unsigned char*)(ws + 2 * szP) : nullptr;
    size_t off = 2 * szP + (fat ? szE8 : 0);
    float* rzbuf  = (float*)(ws + off); off += (size_t)B_ * N_ * sizeof(float);
    float* topv   = (float*)(ws + off); off += (size_t)B_ * N_ * TOPK * sizeof(float);
    int*   topc   = (int*)(ws + off);   off += (size_t)B_ * N_ * TOPK * sizeof(int);
    float* colsum = (float*)(ws + off); off += (size_t)B_ * N_ * sizeof(float);
    int*   mrow   = (int*)(ws + off);   off += 1024;
    int*   mcol   = (int*)(ws + off);

    hipMemsetAsync(colsum, 0, (size_t)B_ * N_ * sizeof(float), stream);

    packbf<<<dim3(N_ / 64, D_ / 64, 2 * B_), 256, 0, stream>>>(srcE, tgtE, srcP, tgtP);
    gemm7<<<dim3(256), 512, 0, stream>>>(srcP, tgtP, rzbuf, topv, topc, e8);
    if (fat)
        colsum3<<<dim3(2, 16, 16), 256, 0, stream>>>(e8, rzbuf, colsum);
    else
        gemm8<<<dim3(512), 512, 0, stream>>>(srcP, tgtP, rzbuf, colsum);
    match2<<<B_, 256, 0, stream>>>(topv, topc, mrow, mcol);
    finish_kernel<<<B_, 256, 0, stream>>>(src, tgt, colsum, mrow, mcol, out);
}